// Round 6
// baseline (587.397 us; speedup 1.0000x reference)
//
#include <hip/hip_runtime.h>
#include <cstdint>
#include <cstddef>

typedef unsigned short u16;
typedef __attribute__((ext_vector_type(8))) short bf16x8;
typedef __attribute__((ext_vector_type(8))) unsigned short u16x8;
typedef __attribute__((ext_vector_type(4))) unsigned short u16x4;
typedef __attribute__((ext_vector_type(4))) float f32x4;

__device__ __forceinline__ unsigned short f2bf(float f) {
    union { float f; uint32_t u; } c; c.f = f;
    uint32_t u = c.u + 0x7fffu + ((c.u >> 16) & 1u);
    return (unsigned short)(u >> 16);
}
__device__ __forceinline__ float bf2f(unsigned short h) {
    union { uint32_t u; float f; } c; c.u = ((uint32_t)h) << 16;
    return c.f;
}
__device__ __forceinline__ uint32_t pkbf(float a, float b) {
    union { float f; uint32_t u; } x, y; x.f = a; y.f = b;
    return ((x.u + 0x8000u) >> 16) | ((y.u + 0x8000u) & 0xFFFF0000u);
}

#define GLDS16(g, l)                                                               \
    __builtin_amdgcn_global_load_lds((const __attribute__((address_space(1))) void*)(g), \
                                     (__attribute__((address_space(3))) void*)(l), 16, 0, 0)

// ---------------------------------------------------------------------------
// fp32 -> bf16 straight convert (x).
// ---------------------------------------------------------------------------
__global__ __launch_bounds__(256) void cvt_x(const float* __restrict__ src,
                                             u16* __restrict__ dst) {
    int i = blockIdx.x * 256 + threadIdx.x;
    const float4* s = (const float4*)src + (size_t)i * 2;
    float4 a = s[0], b = s[1];
    u16x8 o;
    o[0] = f2bf(a.x); o[1] = f2bf(a.y); o[2] = f2bf(a.z); o[3] = f2bf(a.w);
    o[4] = f2bf(b.x); o[5] = f2bf(b.y); o[6] = f2bf(b.z); o[7] = f2bf(b.w);
    *(u16x8*)(dst + (size_t)i * 8) = o;
}

// ---------------------------------------------------------------------------
// Transpose-convert: src fp32 [2048 k][C n] -> dst bf16 [C n][2048 k].
// ---------------------------------------------------------------------------
__global__ __launch_bounds__(256) void tcvt(const float* __restrict__ src,
                                            u16* __restrict__ dst, int C) {
    __shared__ u16 tile[32][33];
    const int t = threadIdx.x;
    const int bx = blockIdx.x, by = blockIdx.y;
    const int tr = t >> 3, tc = (t & 7) << 2;
    float4 f = *(const float4*)&src[(size_t)(by * 32 + tr) * C + bx * 32 + tc];
    tile[tr][tc + 0] = f2bf(f.x); tile[tr][tc + 1] = f2bf(f.y);
    tile[tr][tc + 2] = f2bf(f.z); tile[tr][tc + 3] = f2bf(f.w);
    __syncthreads();
    u16x4 o;
    o[0] = tile[tc + 0][tr]; o[1] = tile[tc + 1][tr];
    o[2] = tile[tc + 2][tr]; o[3] = tile[tc + 3][tr];
    *(u16x4*)&dst[(size_t)(bx * 32 + tr) * 2048 + by * 32 + tc] = o;
}

// Merged transpose-convert for Wq|Wk|Wv -> wqkvt (one launch).
__global__ __launch_bounds__(256) void tcvt3(const float* __restrict__ Wq,
                                             const float* __restrict__ Wk,
                                             const float* __restrict__ Wv,
                                             u16* __restrict__ dst) {
    __shared__ u16 tile[32][33];
    const int t = threadIdx.x;
    const int bxg = blockIdx.x, by = blockIdx.y;
    const float* src; int C, nb; u16* dbase;
    if (bxg < 64)      { src = Wq; C = 2048; nb = bxg;      dbase = dst; }
    else if (bxg < 80) { src = Wk; C = 512;  nb = bxg - 64; dbase = dst + (size_t)2048 * 2048; }
    else               { src = Wv; C = 512;  nb = bxg - 80; dbase = dst + (size_t)2560 * 2048; }
    const int tr = t >> 3, tc = (t & 7) << 2;
    float4 f = *(const float4*)&src[(size_t)(by * 32 + tr) * C + nb * 32 + tc];
    tile[tr][tc + 0] = f2bf(f.x); tile[tr][tc + 1] = f2bf(f.y);
    tile[tr][tc + 2] = f2bf(f.z); tile[tr][tc + 3] = f2bf(f.w);
    __syncthreads();
    u16x4 o;
    o[0] = tile[tc + 0][tr]; o[1] = tile[tc + 1][tr];
    o[2] = tile[tc + 2][tr]; o[3] = tile[tc + 3][tr];
    *(u16x4*)&dbase[(size_t)(nb * 32 + tr) * 2048 + by * 32 + tc] = o;
}

// ---------------------------------------------------------------------------
// m97-style GEMM (BK=32, proven round-4): C = A[Mx2048] * Bt[Nx2048]^T.
// MODE 0: segmented qkv epilogue + fused rope; Q pre-scaled by 1/8*log2e.
// MODE 1: fp32 C, N=2048.
// ---------------------------------------------------------------------------
template <int MODE>
__global__ __launch_bounds__(256) void gemm2(const u16* __restrict__ A,
                                             const u16* __restrict__ Bt,
                                             u16* __restrict__ oq, u16* __restrict__ ok,
                                             u16* __restrict__ ov, float* __restrict__ of) {
    __shared__ u16 As[128 * 32];
    __shared__ u16 Bs[128 * 32];
    const int t = threadIdx.x, w = t >> 6, lane = t & 63;
    const int l15 = lane & 15, quad = lane >> 4;
    const int m0 = blockIdx.y << 7, n0 = blockIdx.x << 7;
    const int K = 2048;
    const int c0 = w * 2, c1 = c0 + 1;
    const int ar0 = c0 * 16 + (lane >> 2), ar1 = c1 * 16 + (lane >> 2);
    const int ac = (lane & 3) << 3;
    const u16* Ap0 = A + (size_t)(m0 + ar0) * K + ac;
    const u16* Ap1 = A + (size_t)(m0 + ar1) * K + ac;
    const u16* Bp0 = Bt + (size_t)(n0 + ar0) * K + ac;
    const u16* Bp1 = Bt + (size_t)(n0 + ar1) * K + ac;
    const int wm = (w >> 1) << 6, wn = (w & 1) << 6;

    f32x4 acc[4][4] = {};

    for (int k0 = 0; k0 < K; k0 += 32) {
        GLDS16(Ap0 + k0, &As[c0 * 512]);
        GLDS16(Ap1 + k0, &As[c1 * 512]);
        GLDS16(Bp0 + k0, &Bs[c0 * 512]);
        GLDS16(Bp1 + k0, &Bs[c1 * 512]);
        __syncthreads();
        bf16x8 a[4], bfr[4];
#pragma unroll
        for (int mt = 0; mt < 4; ++mt)
            a[mt] = *(bf16x8*)&As[(wm + mt * 16 + l15) * 32 + quad * 8];
#pragma unroll
        for (int nt = 0; nt < 4; ++nt)
            bfr[nt] = *(bf16x8*)&Bs[(wn + nt * 16 + l15) * 32 + quad * 8];
#pragma unroll
        for (int mt = 0; mt < 4; ++mt)
#pragma unroll
            for (int nt = 0; nt < 4; ++nt)
                acc[mt][nt] = __builtin_amdgcn_mfma_f32_16x16x32_bf16(a[mt], bfr[nt], acc[mt][nt], 0, 0, 0);
        __syncthreads();
    }

    if constexpr (MODE == 0) {
        const float SC = 0.125f * 1.4426950408889634f;   // folded into Q
        const int colbase = n0 + wn;
        const bool isv = (colbase >= 2560);
        const bool isq = (colbase < 2048);
        float iv[4];
        if (!isv) {
#pragma unroll
            for (int nt = 0; nt < 4; ++nt)
                iv[nt] = exp2f(-0.4152410118609253f * (float)(nt * 8 + (l15 >> 1)));
        }
        const int map1 = (quad << 4) | ((2 * l15 + 1) & 15);
        const int map2 = (quad << 4) | ((2 * l15) & 15);
        const bool lo = (l15 < 8);
#pragma unroll
        for (int mt = 0; mt < 4; ++mt)
#pragma unroll
            for (int r = 0; r < 4; ++r) {
                const int row = m0 + wm + mt * 16 + quad * 4 + r;
                float v0 = acc[mt][0][r], v1 = acc[mt][1][r];
                float v2 = acc[mt][2][r], v3 = acc[mt][3][r];
                float o0 = v0, o1 = v1, o2 = v2, o3 = v3;
                if (!isv) {
                    float g1a = __shfl(v0, map1), g1b = __shfl(v1, map1);
                    float g1c = __shfl(v2, map1), g1d = __shfl(v3, map1);
                    float g2a = __shfl(v0, map2), g2b = __shfl(v1, map2);
                    float g2c = __shfl(v2, map2), g2d = __shfl(v3, map2);
                    float p0 = lo ? g1a : g1b;
                    float p1 = lo ? g1c : g1d;
                    float p2 = lo ? g2a : g2b;
                    float p3 = lo ? g2c : g2d;
                    const float tt = (float)(row & 2047);
                    float sn, cs;
                    __sincosf(tt * iv[0], &sn, &cs); o0 = v0 * cs - p0 * sn;
                    __sincosf(tt * iv[1], &sn, &cs); o1 = v1 * cs - p1 * sn;
                    __sincosf(tt * iv[2], &sn, &cs); o2 = v2 * cs + p2 * sn;
                    __sincosf(tt * iv[3], &sn, &cs); o3 = v3 * cs + p3 * sn;
                    if (isq) { o0 *= SC; o1 *= SC; o2 *= SC; o3 *= SC; }
                }
                float o[4] = {o0, o1, o2, o3};
                if (isq) {
#pragma unroll
                    for (int nt = 0; nt < 4; ++nt)
                        oq[(size_t)row * 2048 + colbase + nt * 16 + l15] = f2bf(o[nt]);
                } else if (colbase < 2560) {
#pragma unroll
                    for (int nt = 0; nt < 4; ++nt)
                        ok[(size_t)row * 512 + colbase - 2048 + nt * 16 + l15] = f2bf(o[nt]);
                } else {
#pragma unroll
                    for (int nt = 0; nt < 4; ++nt)
                        ov[(size_t)(colbase - 2560 + nt * 16 + l15) * 4096 + row] = f2bf(o[nt]);
                }
            }
    } else {
#pragma unroll
        for (int mt = 0; mt < 4; ++mt)
#pragma unroll
            for (int nt = 0; nt < 4; ++nt)
#pragma unroll
                for (int r = 0; r < 4; ++r) {
                    int row = m0 + wm + mt * 16 + quad * 4 + r;
                    int col = n0 + wn + nt * 16 + l15;
                    of[(size_t)row * 2048 + col] = acc[mt][nt][r];
                }
    }
}

// ---------------------------------------------------------------------------
// softmax + PV for one 16-q group on one 64-key tile. Tree reductions.
// av: hoisted V^T frags. Lane: q=l15, keys kt*16+quad*4+r. Q pre-scaled.
// ---------------------------------------------------------------------------
__device__ __forceinline__ void soft_pv(const f32x4 st[4], float& m_i, float& l_i,
                                        f32x4 acc[4], u16* __restrict__ Pq,
                                        const bf16x8 av[4][2],
                                        int l15, int quad, int qg, int keybase, bool diag) {
    float sv[16];
#pragma unroll
    for (int kt = 0; kt < 4; ++kt)
#pragma unroll
        for (int r = 0; r < 4; ++r) sv[kt * 4 + r] = st[kt][r];
    if (diag) {
#pragma unroll
        for (int kt = 0; kt < 4; ++kt)
#pragma unroll
            for (int r = 0; r < 4; ++r) {
                int key = keybase + kt * 16 + quad * 4 + r;
                if (key > qg) sv[kt * 4 + r] = -INFINITY;
            }
    }
    // depth-4 max tree
    float tm[8];
#pragma unroll
    for (int i = 0; i < 8; ++i) tm[i] = fmaxf(sv[i], sv[i + 8]);
#pragma unroll
    for (int i = 0; i < 4; ++i) tm[i] = fmaxf(tm[i], tm[i + 4]);
    float mx = fmaxf(fmaxf(tm[0], tm[1]), fmaxf(tm[2], tm[3]));
    mx = fmaxf(mx, __shfl_xor(mx, 16));
    mx = fmaxf(mx, __shfl_xor(mx, 32));
    float mnew = fmaxf(m_i, mx);
#pragma unroll
    for (int i = 0; i < 16; ++i) sv[i] = __builtin_amdgcn_exp2f(sv[i] - mnew);
    // depth-4 sum tree
    float ts[8];
#pragma unroll
    for (int i = 0; i < 8; ++i) ts[i] = sv[i] + sv[i + 8];
#pragma unroll
    for (int i = 0; i < 4; ++i) ts[i] = ts[i] + ts[i + 4];
    float sum = (ts[0] + ts[1]) + (ts[2] + ts[3]);
    sum += __shfl_xor(sum, 16);
    sum += __shfl_xor(sum, 32);
    float alpha = __builtin_amdgcn_exp2f(m_i - mnew);
    l_i = l_i * alpha + sum;
    m_i = mnew;

#pragma unroll
    for (int kt = 0; kt < 4; ++kt) {
        uint2 uu;
        uu.x = pkbf(sv[kt * 4 + 0], sv[kt * 4 + 1]);
        uu.y = pkbf(sv[kt * 4 + 2], sv[kt * 4 + 3]);
        *(uint2*)&Pq[l15 * 72 + kt * 16 + quad * 4] = uu;
    }
    bf16x8 bp0 = *(bf16x8*)&Pq[l15 * 72 + quad * 8];
    bf16x8 bp1 = *(bf16x8*)&Pq[l15 * 72 + 32 + quad * 8];
#pragma unroll
    for (int dt = 0; dt < 4; ++dt) {
#pragma unroll
        for (int r = 0; r < 4; ++r) acc[dt][r] *= alpha;
        acc[dt] = __builtin_amdgcn_mfma_f32_16x16x32_bf16(av[dt][0], bp0, acc[dt], 0, 0, 0);
        acc[dt] = __builtin_amdgcn_mfma_f32_16x16x32_bf16(av[dt][1], bp1, acc[dt], 0, 0, 0);
    }
}

// ---------------------------------------------------------------------------
// Flash attention v7 — attn4's per-tile structure (32-row group, 2 mt chains,
// 32 MFMAs/staging) but ONE group per block, grid 1024 => 4 blocks/CU.
// g = 63-bx so longest blocks dispatch first.
// ---------------------------------------------------------------------------
__global__ __launch_bounds__(256, 4) void attn7(const u16* __restrict__ q,
                                                const u16* __restrict__ k,
                                                const u16* __restrict__ vT,
                                                u16* __restrict__ att) {
    __shared__ u16 Ks[64 * 72];
    __shared__ u16 Vt[64 * 72];
    __shared__ u16 Pw[4][16 * 72];

    const int t = threadIdx.x, w = t >> 6, lane = t & 63;
    const int l15 = lane & 15, quad = lane >> 4;
    const int g = 63 - (int)blockIdx.x;          // 32-row group, longest first
    const int kvh = blockIdx.y, b = blockIdx.z;
    const int h = kvh * 4 + w;
    const size_t rowbase = (size_t)b * 2048;
    const int sr = t >> 2, sd = (t & 3) << 4;
    u16* Pq = &Pw[w][0];

    const int qbase = g << 5;
    const int ntiles = (g >> 1) + 1;

    bf16x8 aq[2][2];
#pragma unroll
    for (int mt = 0; mt < 2; ++mt)
#pragma unroll
        for (int kc = 0; kc < 2; ++kc)
            aq[mt][kc] = *(const bf16x8*)&q[(rowbase + qbase + mt * 16 + l15) * 2048 +
                                           h * 64 + kc * 32 + quad * 8];

    f32x4 acc[2][4] = {};
    float m_i[2] = {-INFINITY, -INFINITY};
    float l_i[2] = {0.f, 0.f};

    const u16* kbase = &k[(rowbase + sr) * 512 + kvh * 64 + sd];
    const u16* vbase = &vT[(size_t)(kvh * 64 + sr) * 4096 + rowbase + sd];

    // prefetch tile 0
    u16x8 pk0 = *(const u16x8*)kbase;
    u16x8 pk1 = *(const u16x8*)(kbase + 8);
    u16x8 pv0 = *(const u16x8*)vbase;
    u16x8 pv1 = *(const u16x8*)(vbase + 8);

    for (int kb = 0; kb < ntiles; ++kb) {
        __syncthreads();
        *(u16x8*)&Ks[sr * 72 + sd]     = pk0;
        *(u16x8*)&Ks[sr * 72 + sd + 8] = pk1;
        *(u16x8*)&Vt[sr * 72 + sd]     = pv0;
        *(u16x8*)&Vt[sr * 72 + sd + 8] = pv1;
        if (kb + 1 < ntiles) {
            const u16* kp = kbase + (size_t)(kb + 1) * 64 * 512;
            pk0 = *(const u16x8*)kp;
            pk1 = *(const u16x8*)(kp + 8);
            const u16* vp = vbase + (size_t)(kb + 1) * 64;
            pv0 = *(const u16x8*)vp;
            pv1 = *(const u16x8*)(vp + 8);
        }
        __syncthreads();

        // hoisted V^T frags (shared by both mt)
        bf16x8 av[4][2];
#pragma unroll
        for (int dt = 0; dt < 4; ++dt)
#pragma unroll
            for (int kc = 0; kc < 2; ++kc)
                av[dt][kc] = *(bf16x8*)&Vt[(dt * 16 + l15) * 72 + kc * 32 + quad * 8];

        // S^T for both mt, sharing K-frag reads
        f32x4 st[2][4] = {};
#pragma unroll
        for (int kt = 0; kt < 4; ++kt) {
            bf16x8 ak0 = *(bf16x8*)&Ks[(kt * 16 + l15) * 72 + quad * 8];
            bf16x8 ak1 = *(bf16x8*)&Ks[(kt * 16 + l15) * 72 + 32 + quad * 8];
            st[0][kt] = __builtin_amdgcn_mfma_f32_16x16x32_bf16(ak0, aq[0][0], st[0][kt], 0, 0, 0);
            st[0][kt] = __builtin_amdgcn_mfma_f32_16x16x32_bf16(ak1, aq[0][1], st[0][kt], 0, 0, 0);
            st[1][kt] = __builtin_amdgcn_mfma_f32_16x16x32_bf16(ak0, aq[1][0], st[1][kt], 0, 0, 0);
            st[1][kt] = __builtin_amdgcn_mfma_f32_16x16x32_bf16(ak1, aq[1][1], st[1][kt], 0, 0, 0);
        }
        const bool diag = (kb == ntiles - 1);
        soft_pv(st[0], m_i[0], l_i[0], acc[0], Pq, av, l15, quad, qbase + l15, kb * 64, diag);
        soft_pv(st[1], m_i[1], l_i[1], acc[1], Pq, av, l15, quad, qbase + 16 + l15, kb * 64, diag);
    }

    // epilogue: O^T lane(d = dt*16+quad*4+r, q = l15)
#pragma unroll
    for (int mt = 0; mt < 2; ++mt) {
        float inv = 1.0f / l_i[mt];
        size_t row = rowbase + qbase + mt * 16 + l15;
#pragma unroll
        for (int dt = 0; dt < 4; ++dt) {
            uint2 uu;
            uu.x = pkbf(acc[mt][dt][0] * inv, acc[mt][dt][1] * inv);
            uu.y = pkbf(acc[mt][dt][2] * inv, acc[mt][dt][3] * inv);
            *(uint2*)&att[row * 2048 + h * 64 + dt * 16 + quad * 4] = uu;
        }
    }
}

// ---------------------------------------------------------------------------
extern "C" void kernel_launch(void* const* d_in, const int* in_sizes, int n_in,
                              void* d_out, int out_size, void* d_ws, size_t ws_size,
                              hipStream_t stream) {
    const float* x  = (const float*)d_in[0];
    const float* Wq = (const float*)d_in[2];
    const float* Wk = (const float*)d_in[3];
    const float* Wv = (const float*)d_in[4];
    const float* Wo = (const float*)d_in[5];
    float* out = (float*)d_out;

    u16* xb = (u16*)d_out;                                   // bf16 x in d_out (dead before final write)

    u16* q     = (u16*)d_ws;                                 // 4096x2048 (pre-scaled by 1/8*log2e)
    u16* kk    = q + (size_t)4096 * 2048;                    // 4096x512
    u16* vt    = kk + (size_t)4096 * 512;                    // 512x4096 (V^T)
    u16* wqkvt = vt + (size_t)4096 * 512;                    // 3072x2048 (dead after QKV gemm)
    u16* att   = wqkvt;                                      // 4096x2048 aliases dead wqkvt
    u16* wot   = kk;                                         // 2048x2048 aliases dead kk+vt (after attn)

    cvt_x<<<4096, 256, 0, stream>>>(x, xb);
    tcvt3<<<dim3(96, 64), 256, 0, stream>>>(Wq, Wk, Wv, wqkvt);
    gemm2<0><<<dim3(24, 32), 256, 0, stream>>>(xb, wqkvt, q, kk, vt, nullptr);  // rope+scale fused
    attn7<<<dim3(64, 8, 2), 256, 0, stream>>>(q, kk, vt, att);
    tcvt<<<dim3(64, 64), 256, 0, stream>>>(Wo, wot, 2048);
    gemm2<1><<<dim3(16, 32), 256, 0, stream>>>(att, wot, nullptr, nullptr, nullptr, out);
}

// Round 7
// 353.108 us; speedup vs baseline: 1.6635x; 1.6635x over previous
//
#include <hip/hip_runtime.h>
#include <cstdint>
#include <cstddef>

typedef unsigned short u16;
typedef __attribute__((ext_vector_type(8))) short bf16x8;
typedef __attribute__((ext_vector_type(8))) unsigned short u16x8;
typedef __attribute__((ext_vector_type(4))) unsigned short u16x4;
typedef __attribute__((ext_vector_type(4))) float f32x4;

__device__ __forceinline__ unsigned short f2bf(float f) {
    union { float f; uint32_t u; } c; c.f = f;
    uint32_t u = c.u + 0x7fffu + ((c.u >> 16) & 1u);
    return (unsigned short)(u >> 16);
}
__device__ __forceinline__ float bf2f(unsigned short h) {
    union { uint32_t u; float f; } c; c.u = ((uint32_t)h) << 16;
    return c.f;
}
__device__ __forceinline__ uint32_t pkbf(float a, float b) {
    union { float f; uint32_t u; } x, y; x.f = a; y.f = b;
    return ((x.u + 0x8000u) >> 16) | ((y.u + 0x8000u) & 0xFFFF0000u);
}

#define GLDS16(g, l)                                                               \
    __builtin_amdgcn_global_load_lds((const __attribute__((address_space(1))) void*)(g), \
                                     (__attribute__((address_space(3))) void*)(l), 16, 0, 0)

// ---------------------------------------------------------------------------
// fp32 -> bf16 straight convert (x).
// ---------------------------------------------------------------------------
__global__ __launch_bounds__(256) void cvt_x(const float* __restrict__ src,
                                             u16* __restrict__ dst) {
    int i = blockIdx.x * 256 + threadIdx.x;
    const float4* s = (const float4*)src + (size_t)i * 2;
    float4 a = s[0], b = s[1];
    u16x8 o;
    o[0] = f2bf(a.x); o[1] = f2bf(a.y); o[2] = f2bf(a.z); o[3] = f2bf(a.w);
    o[4] = f2bf(b.x); o[5] = f2bf(b.y); o[6] = f2bf(b.z); o[7] = f2bf(b.w);
    *(u16x8*)(dst + (size_t)i * 8) = o;
}

// ---------------------------------------------------------------------------
// Transpose-convert: src fp32 [2048 k][C n] -> dst bf16 [C n][2048 k].
// ---------------------------------------------------------------------------
__global__ __launch_bounds__(256) void tcvt(const float* __restrict__ src,
                                            u16* __restrict__ dst, int C) {
    __shared__ u16 tile[32][33];
    const int t = threadIdx.x;
    const int bx = blockIdx.x, by = blockIdx.y;
    const int tr = t >> 3, tc = (t & 7) << 2;
    float4 f = *(const float4*)&src[(size_t)(by * 32 + tr) * C + bx * 32 + tc];
    tile[tr][tc + 0] = f2bf(f.x); tile[tr][tc + 1] = f2bf(f.y);
    tile[tr][tc + 2] = f2bf(f.z); tile[tr][tc + 3] = f2bf(f.w);
    __syncthreads();
    u16x4 o;
    o[0] = tile[tc + 0][tr]; o[1] = tile[tc + 1][tr];
    o[2] = tile[tc + 2][tr]; o[3] = tile[tc + 3][tr];
    *(u16x4*)&dst[(size_t)(bx * 32 + tr) * 2048 + by * 32 + tc] = o;
}

// Merged transpose-convert for Wq|Wk|Wv -> wqkvt (one launch).
__global__ __launch_bounds__(256) void tcvt3(const float* __restrict__ Wq,
                                             const float* __restrict__ Wk,
                                             const float* __restrict__ Wv,
                                             u16* __restrict__ dst) {
    __shared__ u16 tile[32][33];
    const int t = threadIdx.x;
    const int bxg = blockIdx.x, by = blockIdx.y;
    const float* src; int C, nb; u16* dbase;
    if (bxg < 64)      { src = Wq; C = 2048; nb = bxg;      dbase = dst; }
    else if (bxg < 80) { src = Wk; C = 512;  nb = bxg - 64; dbase = dst + (size_t)2048 * 2048; }
    else               { src = Wv; C = 512;  nb = bxg - 80; dbase = dst + (size_t)2560 * 2048; }
    const int tr = t >> 3, tc = (t & 7) << 2;
    float4 f = *(const float4*)&src[(size_t)(by * 32 + tr) * C + nb * 32 + tc];
    tile[tr][tc + 0] = f2bf(f.x); tile[tr][tc + 1] = f2bf(f.y);
    tile[tr][tc + 2] = f2bf(f.z); tile[tr][tc + 3] = f2bf(f.w);
    __syncthreads();
    u16x4 o;
    o[0] = tile[tc + 0][tr]; o[1] = tile[tc + 1][tr];
    o[2] = tile[tc + 2][tr]; o[3] = tile[tc + 3][tr];
    *(u16x4*)&dbase[(size_t)(nb * 32 + tr) * 2048 + by * 32 + tc] = o;
}

// ---------------------------------------------------------------------------
// m97-style GEMM (BK=32, proven round-4): C = A[Mx2048] * Bt[Nx2048]^T.
// MODE 0: segmented qkv epilogue + fused rope; Q pre-scaled by 1/8*log2e.
// MODE 1: fp32 C, N=2048.
// ---------------------------------------------------------------------------
template <int MODE>
__global__ __launch_bounds__(256) void gemm2(const u16* __restrict__ A,
                                             const u16* __restrict__ Bt,
                                             u16* __restrict__ oq, u16* __restrict__ ok,
                                             u16* __restrict__ ov, float* __restrict__ of) {
    __shared__ u16 As[128 * 32];
    __shared__ u16 Bs[128 * 32];
    const int t = threadIdx.x, w = t >> 6, lane = t & 63;
    const int l15 = lane & 15, quad = lane >> 4;
    const int m0 = blockIdx.y << 7, n0 = blockIdx.x << 7;
    const int K = 2048;
    const int c0 = w * 2, c1 = c0 + 1;
    const int ar0 = c0 * 16 + (lane >> 2), ar1 = c1 * 16 + (lane >> 2);
    const int ac = (lane & 3) << 3;
    const u16* Ap0 = A + (size_t)(m0 + ar0) * K + ac;
    const u16* Ap1 = A + (size_t)(m0 + ar1) * K + ac;
    const u16* Bp0 = Bt + (size_t)(n0 + ar0) * K + ac;
    const u16* Bp1 = Bt + (size_t)(n0 + ar1) * K + ac;
    const int wm = (w >> 1) << 6, wn = (w & 1) << 6;

    f32x4 acc[4][4] = {};

    for (int k0 = 0; k0 < K; k0 += 32) {
        GLDS16(Ap0 + k0, &As[c0 * 512]);
        GLDS16(Ap1 + k0, &As[c1 * 512]);
        GLDS16(Bp0 + k0, &Bs[c0 * 512]);
        GLDS16(Bp1 + k0, &Bs[c1 * 512]);
        __syncthreads();
        bf16x8 a[4], bfr[4];
#pragma unroll
        for (int mt = 0; mt < 4; ++mt)
            a[mt] = *(bf16x8*)&As[(wm + mt * 16 + l15) * 32 + quad * 8];
#pragma unroll
        for (int nt = 0; nt < 4; ++nt)
            bfr[nt] = *(bf16x8*)&Bs[(wn + nt * 16 + l15) * 32 + quad * 8];
#pragma unroll
        for (int mt = 0; mt < 4; ++mt)
#pragma unroll
            for (int nt = 0; nt < 4; ++nt)
                acc[mt][nt] = __builtin_amdgcn_mfma_f32_16x16x32_bf16(a[mt], bfr[nt], acc[mt][nt], 0, 0, 0);
        __syncthreads();
    }

    if constexpr (MODE == 0) {
        const float SC = 0.125f * 1.4426950408889634f;   // folded into Q
        const int colbase = n0 + wn;
        const bool isv = (colbase >= 2560);
        const bool isq = (colbase < 2048);
        float iv[4];
        if (!isv) {
#pragma unroll
            for (int nt = 0; nt < 4; ++nt)
                iv[nt] = exp2f(-0.4152410118609253f * (float)(nt * 8 + (l15 >> 1)));
        }
        const int map1 = (quad << 4) | ((2 * l15 + 1) & 15);
        const int map2 = (quad << 4) | ((2 * l15) & 15);
        const bool lo = (l15 < 8);
#pragma unroll
        for (int mt = 0; mt < 4; ++mt)
#pragma unroll
            for (int r = 0; r < 4; ++r) {
                const int row = m0 + wm + mt * 16 + quad * 4 + r;
                float v0 = acc[mt][0][r], v1 = acc[mt][1][r];
                float v2 = acc[mt][2][r], v3 = acc[mt][3][r];
                float o0 = v0, o1 = v1, o2 = v2, o3 = v3;
                if (!isv) {
                    float g1a = __shfl(v0, map1), g1b = __shfl(v1, map1);
                    float g1c = __shfl(v2, map1), g1d = __shfl(v3, map1);
                    float g2a = __shfl(v0, map2), g2b = __shfl(v1, map2);
                    float g2c = __shfl(v2, map2), g2d = __shfl(v3, map2);
                    float p0 = lo ? g1a : g1b;
                    float p1 = lo ? g1c : g1d;
                    float p2 = lo ? g2a : g2b;
                    float p3 = lo ? g2c : g2d;
                    const float tt = (float)(row & 2047);
                    float sn, cs;
                    __sincosf(tt * iv[0], &sn, &cs); o0 = v0 * cs - p0 * sn;
                    __sincosf(tt * iv[1], &sn, &cs); o1 = v1 * cs - p1 * sn;
                    __sincosf(tt * iv[2], &sn, &cs); o2 = v2 * cs + p2 * sn;
                    __sincosf(tt * iv[3], &sn, &cs); o3 = v3 * cs + p3 * sn;
                    if (isq) { o0 *= SC; o1 *= SC; o2 *= SC; o3 *= SC; }
                }
                float o[4] = {o0, o1, o2, o3};
                if (isq) {
#pragma unroll
                    for (int nt = 0; nt < 4; ++nt)
                        oq[(size_t)row * 2048 + colbase + nt * 16 + l15] = f2bf(o[nt]);
                } else if (colbase < 2560) {
#pragma unroll
                    for (int nt = 0; nt < 4; ++nt)
                        ok[(size_t)row * 512 + colbase - 2048 + nt * 16 + l15] = f2bf(o[nt]);
                } else {
#pragma unroll
                    for (int nt = 0; nt < 4; ++nt)
                        ov[(size_t)(colbase - 2560 + nt * 16 + l15) * 4096 + row] = f2bf(o[nt]);
                }
            }
    } else {
#pragma unroll
        for (int mt = 0; mt < 4; ++mt)
#pragma unroll
            for (int nt = 0; nt < 4; ++nt)
#pragma unroll
                for (int r = 0; r < 4; ++r) {
                    int row = m0 + wm + mt * 16 + quad * 4 + r;
                    int col = n0 + wn + nt * 16 + l15;
                    of[(size_t)row * 2048 + col] = acc[mt][nt][r];
                }
    }
}

// ---------------------------------------------------------------------------
// softmax + PV for one 16-q group on one 64-key tile. Tree reductions.
// V frags read from LDS inside the dt loop (low register pressure).
// Lane: q=l15, keys kt*16+quad*4+r. Q pre-scaled by 1/8*log2e.
// ---------------------------------------------------------------------------
__device__ __forceinline__ void soft_pv(const f32x4 st[4], float& m_i, float& l_i,
                                        f32x4 acc[4], u16* __restrict__ Pq,
                                        const u16* __restrict__ Vt,
                                        int l15, int quad, int qg, int keybase, bool diag) {
    float sv[16];
#pragma unroll
    for (int kt = 0; kt < 4; ++kt)
#pragma unroll
        for (int r = 0; r < 4; ++r) sv[kt * 4 + r] = st[kt][r];
    if (diag) {
#pragma unroll
        for (int kt = 0; kt < 4; ++kt)
#pragma unroll
            for (int r = 0; r < 4; ++r) {
                int key = keybase + kt * 16 + quad * 4 + r;
                if (key > qg) sv[kt * 4 + r] = -INFINITY;
            }
    }
    // depth-4 max tree
    float tm[8];
#pragma unroll
    for (int i = 0; i < 8; ++i) tm[i] = fmaxf(sv[i], sv[i + 8]);
#pragma unroll
    for (int i = 0; i < 4; ++i) tm[i] = fmaxf(tm[i], tm[i + 4]);
    float mx = fmaxf(fmaxf(tm[0], tm[1]), fmaxf(tm[2], tm[3]));
    mx = fmaxf(mx, __shfl_xor(mx, 16));
    mx = fmaxf(mx, __shfl_xor(mx, 32));
    float mnew = fmaxf(m_i, mx);
#pragma unroll
    for (int i = 0; i < 16; ++i) sv[i] = __builtin_amdgcn_exp2f(sv[i] - mnew);
    // depth-4 sum tree
    float ts[8];
#pragma unroll
    for (int i = 0; i < 8; ++i) ts[i] = sv[i] + sv[i + 8];
#pragma unroll
    for (int i = 0; i < 4; ++i) ts[i] = ts[i] + ts[i + 4];
    float sum = (ts[0] + ts[1]) + (ts[2] + ts[3]);
    sum += __shfl_xor(sum, 16);
    sum += __shfl_xor(sum, 32);
    float alpha = __builtin_amdgcn_exp2f(m_i - mnew);
    l_i = l_i * alpha + sum;
    m_i = mnew;

#pragma unroll
    for (int kt = 0; kt < 4; ++kt) {
        uint2 uu;
        uu.x = pkbf(sv[kt * 4 + 0], sv[kt * 4 + 1]);
        uu.y = pkbf(sv[kt * 4 + 2], sv[kt * 4 + 3]);
        *(uint2*)&Pq[l15 * 72 + kt * 16 + quad * 4] = uu;
    }
    bf16x8 bp0 = *(bf16x8*)&Pq[l15 * 72 + quad * 8];
    bf16x8 bp1 = *(bf16x8*)&Pq[l15 * 72 + 32 + quad * 8];
#pragma unroll
    for (int dt = 0; dt < 4; ++dt) {
        bf16x8 av0 = *(const bf16x8*)&Vt[(dt * 16 + l15) * 72 + quad * 8];
        bf16x8 av1 = *(const bf16x8*)&Vt[(dt * 16 + l15) * 72 + 32 + quad * 8];
#pragma unroll
        for (int r = 0; r < 4; ++r) acc[dt][r] *= alpha;
        acc[dt] = __builtin_amdgcn_mfma_f32_16x16x32_bf16(av0, bp0, acc[dt], 0, 0, 0);
        acc[dt] = __builtin_amdgcn_mfma_f32_16x16x32_bf16(av1, bp1, acc[dt], 0, 0, 0);
    }
}

// ---------------------------------------------------------------------------
// Flash attention v7b — attn4's exact per-tile structure (32-row group,
// two mt chains, 32 MFMAs/staging), ONE group per block, grid 1024.
// launch_bounds(256,3): attn4's proven no-spill cap (VGPR ~84-130).
// g = 63-bx so longest blocks dispatch first.
// ---------------------------------------------------------------------------
__global__ __launch_bounds__(256, 3) void attn7(const u16* __restrict__ q,
                                                const u16* __restrict__ k,
                                                const u16* __restrict__ vT,
                                                u16* __restrict__ att) {
    __shared__ u16 Ks[64 * 72];
    __shared__ u16 Vt[64 * 72];
    __shared__ u16 Pw[4][16 * 72];

    const int t = threadIdx.x, w = t >> 6, lane = t & 63;
    const int l15 = lane & 15, quad = lane >> 4;
    const int g = 63 - (int)blockIdx.x;          // 32-row group, longest first
    const int kvh = blockIdx.y, b = blockIdx.z;
    const int h = kvh * 4 + w;
    const size_t rowbase = (size_t)b * 2048;
    const int sr = t >> 2, sd = (t & 3) << 4;
    u16* Pq = &Pw[w][0];

    const int qbase = g << 5;
    const int ntiles = (g >> 1) + 1;

    bf16x8 aq[2][2];
#pragma unroll
    for (int mt = 0; mt < 2; ++mt)
#pragma unroll
        for (int kc = 0; kc < 2; ++kc)
            aq[mt][kc] = *(const bf16x8*)&q[(rowbase + qbase + mt * 16 + l15) * 2048 +
                                           h * 64 + kc * 32 + quad * 8];

    f32x4 acc[2][4] = {};
    float m_i[2] = {-INFINITY, -INFINITY};
    float l_i[2] = {0.f, 0.f};

    const u16* kbase = &k[(rowbase + sr) * 512 + kvh * 64 + sd];
    const u16* vbase = &vT[(size_t)(kvh * 64 + sr) * 4096 + rowbase + sd];

    // prefetch tile 0
    u16x8 pk0 = *(const u16x8*)kbase;
    u16x8 pk1 = *(const u16x8*)(kbase + 8);
    u16x8 pv0 = *(const u16x8*)vbase;
    u16x8 pv1 = *(const u16x8*)(vbase + 8);

    for (int kb = 0; kb < ntiles; ++kb) {
        __syncthreads();
        *(u16x8*)&Ks[sr * 72 + sd]     = pk0;
        *(u16x8*)&Ks[sr * 72 + sd + 8] = pk1;
        *(u16x8*)&Vt[sr * 72 + sd]     = pv0;
        *(u16x8*)&Vt[sr * 72 + sd + 8] = pv1;
        if (kb + 1 < ntiles) {
            const u16* kp = kbase + (size_t)(kb + 1) * 64 * 512;
            pk0 = *(const u16x8*)kp;
            pk1 = *(const u16x8*)(kp + 8);
            const u16* vp = vbase + (size_t)(kb + 1) * 64;
            pv0 = *(const u16x8*)vp;
            pv1 = *(const u16x8*)(vp + 8);
        }
        __syncthreads();

        // S^T for both mt, sharing K-frag reads
        f32x4 st[2][4] = {};
#pragma unroll
        for (int kt = 0; kt < 4; ++kt) {
            bf16x8 ak0 = *(bf16x8*)&Ks[(kt * 16 + l15) * 72 + quad * 8];
            bf16x8 ak1 = *(bf16x8*)&Ks[(kt * 16 + l15) * 72 + 32 + quad * 8];
            st[0][kt] = __builtin_amdgcn_mfma_f32_16x16x32_bf16(ak0, aq[0][0], st[0][kt], 0, 0, 0);
            st[0][kt] = __builtin_amdgcn_mfma_f32_16x16x32_bf16(ak1, aq[0][1], st[0][kt], 0, 0, 0);
            st[1][kt] = __builtin_amdgcn_mfma_f32_16x16x32_bf16(ak0, aq[1][0], st[1][kt], 0, 0, 0);
            st[1][kt] = __builtin_amdgcn_mfma_f32_16x16x32_bf16(ak1, aq[1][1], st[1][kt], 0, 0, 0);
        }
        const bool diag = (kb == ntiles - 1);
        soft_pv(st[0], m_i[0], l_i[0], acc[0], Pq, Vt, l15, quad, qbase + l15, kb * 64, diag);
        soft_pv(st[1], m_i[1], l_i[1], acc[1], Pq, Vt, l15, quad, qbase + 16 + l15, kb * 64, diag);
    }

    // epilogue: O^T lane(d = dt*16+quad*4+r, q = l15)
#pragma unroll
    for (int mt = 0; mt < 2; ++mt) {
        float inv = 1.0f / l_i[mt];
        size_t row = rowbase + qbase + mt * 16 + l15;
#pragma unroll
        for (int dt = 0; dt < 4; ++dt) {
            uint2 uu;
            uu.x = pkbf(acc[mt][dt][0] * inv, acc[mt][dt][1] * inv);
            uu.y = pkbf(acc[mt][dt][2] * inv, acc[mt][dt][3] * inv);
            *(uint2*)&att[row * 2048 + h * 64 + dt * 16 + quad * 4] = uu;
        }
    }
}

// ---------------------------------------------------------------------------
extern "C" void kernel_launch(void* const* d_in, const int* in_sizes, int n_in,
                              void* d_out, int out_size, void* d_ws, size_t ws_size,
                              hipStream_t stream) {
    const float* x  = (const float*)d_in[0];
    const float* Wq = (const float*)d_in[2];
    const float* Wk = (const float*)d_in[3];
    const float* Wv = (const float*)d_in[4];
    const float* Wo = (const float*)d_in[5];
    float* out = (float*)d_out;

    u16* xb = (u16*)d_out;                                   // bf16 x in d_out (dead before final write)

    u16* q     = (u16*)d_ws;                                 // 4096x2048 (pre-scaled by 1/8*log2e)
    u16* kk    = q + (size_t)4096 * 2048;                    // 4096x512
    u16* vt    = kk + (size_t)4096 * 512;                    // 512x4096 (V^T)
    u16* wqkvt = vt + (size_t)4096 * 512;                    // 3072x2048 (dead after QKV gemm)
    u16* att   = wqkvt;                                      // 4096x2048 aliases dead wqkvt
    u16* wot   = kk;                                         // 2048x2048 aliases dead kk+vt (after attn)

    cvt_x<<<4096, 256, 0, stream>>>(x, xb);
    tcvt3<<<dim3(96, 64), 256, 0, stream>>>(Wq, Wk, Wv, wqkvt);
    gemm2<0><<<dim3(24, 32), 256, 0, stream>>>(xb, wqkvt, q, kk, vt, nullptr);  // rope+scale fused
    attn7<<<dim3(64, 8, 2), 256, 0, stream>>>(q, kk, vt, att);
    tcvt<<<dim3(64, 64), 256, 0, stream>>>(Wo, wot, 2048);
    gemm2<1><<<dim3(16, 32), 256, 0, stream>>>(att, wot, nullptr, nullptr, nullptr, out);
}